// Round 2
// baseline (371.990 us; speedup 1.0000x reference)
//
#include <hip/hip_runtime.h>
#include <cfloat>

// Geometry: z (32,256,32,32) f32, W (1024,256) f32.
// P = 32768 positions (p = n*1024+hw), K = 256, CODES = 1024.
// d_out = [quantized 8388608][straight_through 8388608][indices-as-float 32768]

#define P_TOTAL   32768
#define N_CODES   1024
#define Q_ELEMS   8388608

// ws layout (floats)
#define WS_ZSQ    0
#define WS_WSQ    32768
#define WS_PD     33792            // [2][32768] partial best distance
#define WS_PI     99328            // [2][32768] partial best index (as float)
#define WS_WT     164864           // Wt[256][1024]

#define GLOAD16(gsrc, ldst) \
  __builtin_amdgcn_global_load_lds((const __attribute__((address_space(1))) void*)(gsrc), \
                                   (__attribute__((address_space(3))) void*)(ldst), 16, 0, 0)

// keep numpy's "square separately, then sum" rounding (block fma contraction)
__device__ __forceinline__ float sq_sep(float v) {
    float t = v * v;
    asm volatile("" : "+v"(t));
    return t;
}

// ---------------------------------------------------------------------------
// k0: transpose W[1024][256] -> Wt[256][1024]  (enables linear-LDS B staging)
// ---------------------------------------------------------------------------
__global__ void k0_transpose(const float* __restrict__ wemb, float* __restrict__ wt) {
    __shared__ float tile[64 * 65];
    const int tid = threadIdx.x;
    const int ct = blockIdx.x >> 2, kt = blockIdx.x & 3;
    const int c0 = ct * 64, k0 = kt * 64;
    const int rr = tid >> 4, cg = tid & 15;
    #pragma unroll
    for (int i = 0; i < 4; ++i) {
        const int row = i * 16 + rr;                       // c within tile
        const float4 v = *(const float4*)&wemb[(size_t)(c0 + row) * 256 + k0 + cg * 4];
        tile[row * 65 + cg * 4 + 0] = v.x;
        tile[row * 65 + cg * 4 + 1] = v.y;
        tile[row * 65 + cg * 4 + 2] = v.z;
        tile[row * 65 + cg * 4 + 3] = v.w;
    }
    __syncthreads();
    #pragma unroll
    for (int i = 0; i < 4; ++i) {
        const int krow = i * 16 + rr;                      // k within tile
        float4 v;
        v.x = tile[(cg * 4 + 0) * 65 + krow];
        v.y = tile[(cg * 4 + 1) * 65 + krow];
        v.z = tile[(cg * 4 + 2) * 65 + krow];
        v.w = tile[(cg * 4 + 3) * 65 + krow];
        *(float4*)&wt[(size_t)(k0 + krow) * 1024 + c0 + cg * 4] = v;
    }
}

// ---------------------------------------------------------------------------
// k1: zsq[p] / wsq[c] with numpy pairwise order (128+128, 8 accumulators)
// ---------------------------------------------------------------------------
__global__ void k1_sums(const float* __restrict__ z, const float* __restrict__ wemb,
                        float* __restrict__ zsq, float* __restrict__ wsq) {
    const int b = blockIdx.x;
    const int tid = threadIdx.x;
    if (b < 128) {
        const int p = b * 256 + tid;
        const int n = p >> 10, hw = p & 1023;
        const float* base = z + (((size_t)(n * 256)) << 10) + hw;
        float half[2];
        #pragma unroll
        for (int h = 0; h < 2; ++h) {
            const float* x = base + (((size_t)(h * 128)) << 10);
            float r[8];
            #pragma unroll
            for (int j = 0; j < 8; ++j) r[j] = sq_sep(x[((size_t)j) << 10]);
            for (int i = 8; i < 128; i += 8) {
                #pragma unroll
                for (int j = 0; j < 8; ++j) r[j] += sq_sep(x[((size_t)(i + j)) << 10]);
            }
            half[h] = ((r[0] + r[1]) + (r[2] + r[3])) + ((r[4] + r[5]) + (r[6] + r[7]));
        }
        zsq[p] = half[0] + half[1];
    } else {
        const int c = (b - 128) * 256 + tid;
        const float* base = wemb + (size_t)c * 256;
        float half[2];
        #pragma unroll
        for (int h = 0; h < 2; ++h) {
            const float* x = base + h * 128;
            float r[8];
            #pragma unroll
            for (int j = 0; j < 8; ++j) r[j] = sq_sep(x[j]);
            for (int i = 8; i < 128; i += 8) {
                #pragma unroll
                for (int j = 0; j < 8; ++j) r[j] += sq_sep(x[i + j]);
            }
            half[h] = ((r[0] + r[1]) + (r[2] + r[3])) + ((r[4] + r[5]) + (r[6] + r[7]));
        }
        wsq[c] = half[0] + half[1];
    }
}

// ---------------------------------------------------------------------------
// k2: fused GEMM + argmin over a 512-code half.
// Grid 1024: pg = bid>>1 (64 positions), half = bid&1 (codes half*512..+512).
// 256 threads = 16 tr x 16 tc. Per thread: 4 pos x 16 codes, acc[4][16].
// K staged 16 at a time via global_load_lds (linear LDS, no conflicts).
// fma chain strictly k-ascending => bitwise-identical distances to R1 kernel.
// ---------------------------------------------------------------------------
__launch_bounds__(256, 4)
__global__ void k2_argmin(const float* __restrict__ z, const float* __restrict__ wt,
                          const float* __restrict__ zsq, const float* __restrict__ wsq,
                          float* __restrict__ pd, float* __restrict__ pi) {
    __shared__ float As[16 * 64];    // [k][m] 4 KB
    __shared__ float Bs[16 * 256];   // [k][c] 16 KB
    __shared__ float wsqs[512];      // this half's code norms

    const int tid = threadIdx.x;
    const int bid = blockIdx.x;
    const int pg = bid >> 1, half = bid & 1;
    const int tc = tid & 15, tr = tid >> 4;
    const int w = tid >> 6, l = tid & 63;
    const int p0 = pg * 64;
    const int n = p0 >> 10, hw0 = p0 & 1023;
    const int chalf = half * 512;

    wsqs[tid]       = wsq[chalf + tid];
    wsqs[tid + 256] = wsq[chalf + tid + 256];

    float zr[4];
    #pragma unroll
    for (int m = 0; m < 4; ++m) zr[m] = zsq[p0 + tr * 4 + m];

    float rmin[4];
    int ridx[4];
    #pragma unroll
    for (int m = 0; m < 4; ++m) { rmin[m] = FLT_MAX; ridx[m] = 0; }

    for (int cc = 0; cc < 2; ++cc) {
        const int cb = chalf + cc * 256;
        float acc[4][16];
        #pragma unroll
        for (int m = 0; m < 4; ++m)
            #pragma unroll
            for (int j = 0; j < 16; ++j) acc[m][j] = 0.0f;

        for (int kc = 0; kc < 16; ++kc) {
            const int k0 = kc * 16;
            __syncthreads();   // prior tile reads done before overwrite
            // A tile: rows k0..k0+15 of z (m-contiguous), 1 call/wave
            GLOAD16(z + ((size_t)(n * 256 + k0 + 4 * w + (l >> 4)) << 10) + hw0 + (l & 15) * 4,
                    &As[w * 256]);
            // B tile: rows k0..k0+15 of Wt, cols cb..cb+255, 4 calls/wave
            #pragma unroll
            for (int j = 0; j < 4; ++j) {
                GLOAD16(wt + ((size_t)(k0 + w * 4 + j) << 10) + cb + l * 4,
                        &Bs[(w * 4 + j) * 256]);
            }
            __syncthreads();   // drains vmcnt -> tiles visible

            #pragma unroll
            for (int kk = 0; kk < 16; ++kk) {
                const float4 a = *(const float4*)&As[kk * 64 + tr * 4];
                const float am[4] = {a.x, a.y, a.z, a.w};
                float bb[16];
                #pragma unroll
                for (int j = 0; j < 4; ++j) {
                    const float4 b = *(const float4*)&Bs[kk * 256 + (j * 16 + tc) * 4];
                    bb[j * 4 + 0] = b.x; bb[j * 4 + 1] = b.y;
                    bb[j * 4 + 2] = b.z; bb[j * 4 + 3] = b.w;
                }
                #pragma unroll
                for (int m = 0; m < 4; ++m)
                    #pragma unroll
                    for (int j = 0; j < 16; ++j)
                        acc[m][j] = __builtin_fmaf(am[m], bb[j], acc[m][j]);
            }
        }
        // per-chunk argmin epilogue (ascending code order within thread)
        #pragma unroll
        for (int m = 0; m < 4; ++m) {
            float bd = FLT_MAX;
            int bi = 0;
            #pragma unroll
            for (int j = 0; j < 4; ++j)
                #pragma unroll
                for (int e = 0; e < 4; ++e) {
                    const int cl = (j * 16 + tc) * 4 + e;       // 0..255
                    const float d = __builtin_fmaf(-2.0f, acc[m][j * 4 + e], zr[m])
                                    + wsqs[cc * 256 + cl];
                    if (d < bd) { bd = d; bi = cb + cl; }       // strict <: first wins
                }
            #pragma unroll
            for (int off = 1; off < 16; off <<= 1) {
                const float od = __shfl_xor(bd, off);
                const int   oi = __shfl_xor(bi, off);
                if (od < bd || (od == bd && oi < bi)) { bd = od; bi = oi; }
            }
            if (bd < rmin[m] || (bd == rmin[m] && bi < ridx[m])) { rmin[m] = bd; ridx[m] = bi; }
        }
    }
    if (tc == 0) {
        #pragma unroll
        for (int m = 0; m < 4; ++m) {
            pd[half * P_TOTAL + p0 + tr * 4 + m] = rmin[m];
            pi[half * P_TOTAL + p0 + tr * 4 + m] = (float)ridx[m];
        }
    }
}

// ---------------------------------------------------------------------------
// k2b: combine the two code-halves (tie -> half 0 = lower index)
// ---------------------------------------------------------------------------
__global__ void k2b_combine(const float* __restrict__ pd, const float* __restrict__ pi,
                            float* __restrict__ idx_out) {
    const int p = blockIdx.x * 256 + threadIdx.x;
    const float d0 = pd[p], d1 = pd[P_TOTAL + p];
    idx_out[p] = (d1 < d0) ? pi[P_TOTAL + p] : pi[p];
}

// ---------------------------------------------------------------------------
// k3: gather + straight-through, NCHW float4 writes
// ---------------------------------------------------------------------------
__global__ void k3_gather(const float* __restrict__ z, const float* __restrict__ wemb,
                          const float* __restrict__ idxf,
                          float* __restrict__ out0, float* __restrict__ out1) {
    const int t = blockIdx.x * 256 + threadIdx.x;
    const int hw4 = t & 255, c = (t >> 8) & 255, n = t >> 16;
    const size_t zo = (((size_t)(n * 256 + c)) << 10) + hw4 * 4;
    const float4 zv = *(const float4*)&z[zo];
    const float4 iv = *(const float4*)&idxf[n * 1024 + hw4 * 4];
    float4 q, st;
    {
        const int i0 = (int)iv.x; q.x = wemb[(size_t)i0 * 256 + c]; st.x = (q.x - zv.x) + zv.x;
        const int i1 = (int)iv.y; q.y = wemb[(size_t)i1 * 256 + c]; st.y = (q.y - zv.y) + zv.y;
        const int i2 = (int)iv.z; q.z = wemb[(size_t)i2 * 256 + c]; st.z = (q.z - zv.z) + zv.z;
        const int i3 = (int)iv.w; q.w = wemb[(size_t)i3 * 256 + c]; st.w = (q.w - zv.w) + zv.w;
    }
    *(float4*)&out0[zo] = q;
    *(float4*)&out1[zo] = st;
}

extern "C" void kernel_launch(void* const* d_in, const int* in_sizes, int n_in,
                              void* d_out, int out_size, void* d_ws, size_t ws_size,
                              hipStream_t stream) {
    const float* z = (const float*)d_in[0];
    const float* wemb = (const float*)d_in[1];
    float* out = (float*)d_out;
    float* out0 = out;
    float* out1 = out + Q_ELEMS;
    float* oidx = out + 2 * Q_ELEMS;
    float* ws = (float*)d_ws;
    float* zsq = ws + WS_ZSQ;
    float* wsq = ws + WS_WSQ;
    float* pd  = ws + WS_PD;
    float* pi  = ws + WS_PI;
    float* wt  = ws + WS_WT;

    k0_transpose<<<64, 256, 0, stream>>>(wemb, wt);
    k1_sums<<<132, 256, 0, stream>>>(z, wemb, zsq, wsq);
    k2_argmin<<<1024, 256, 0, stream>>>(z, wt, zsq, wsq, pd, pi);
    k2b_combine<<<128, 256, 0, stream>>>(pd, pi, oidx);
    k3_gather<<<Q_ELEMS / 4 / 256, 256, 0, stream>>>(z, wemb, oidx, out0, out1);
}

// Round 3
// 307.349 us; speedup vs baseline: 1.2103x; 1.2103x over previous
//
#include <hip/hip_runtime.h>
#include <cfloat>

// Geometry: z (32,256,32,32) f32, W (1024,256) f32.
// P = 32768 positions (p = n*1024+hw), K = 256, CODES = 1024.
// d_out = [quantized 8388608][straight_through 8388608][indices-as-float 32768]

#define P_TOTAL   32768
#define N_CODES   1024
#define Q_ELEMS   8388608

// ws layout (floats)
#define WS_ZSQ    0
#define WS_WSQ    32768
#define WS_PD     33792             // [4][32768] partial best distance
#define WS_PI     164864            // [4][32768] partial best index (as float)
#define WS_WT     295936            // Wt[256][1024]

#define GLOAD16(gsrc, ldst) \
  __builtin_amdgcn_global_load_lds((const __attribute__((address_space(1))) void*)(gsrc), \
                                   (__attribute__((address_space(3))) void*)(ldst), 16, 0, 0)

// keep numpy's "square separately, then sum" rounding (block fma contraction)
__device__ __forceinline__ float sq_sep(float v) {
    float t = v * v;
    asm volatile("" : "+v"(t));
    return t;
}

// ---------------------------------------------------------------------------
// k0: transpose W[1024][256] -> Wt[256][1024]
// ---------------------------------------------------------------------------
__global__ void k0_transpose(const float* __restrict__ wemb, float* __restrict__ wt) {
    __shared__ float tile[64 * 65];
    const int tid = threadIdx.x;
    const int ct = blockIdx.x >> 2, kt = blockIdx.x & 3;
    const int c0 = ct * 64, k0 = kt * 64;
    const int rr = tid >> 4, cg = tid & 15;
    #pragma unroll
    for (int i = 0; i < 4; ++i) {
        const int row = i * 16 + rr;
        const float4 v = *(const float4*)&wemb[(size_t)(c0 + row) * 256 + k0 + cg * 4];
        tile[row * 65 + cg * 4 + 0] = v.x;
        tile[row * 65 + cg * 4 + 1] = v.y;
        tile[row * 65 + cg * 4 + 2] = v.z;
        tile[row * 65 + cg * 4 + 3] = v.w;
    }
    __syncthreads();
    #pragma unroll
    for (int i = 0; i < 4; ++i) {
        const int krow = i * 16 + rr;
        float4 v;
        v.x = tile[(cg * 4 + 0) * 65 + krow];
        v.y = tile[(cg * 4 + 1) * 65 + krow];
        v.z = tile[(cg * 4 + 2) * 65 + krow];
        v.w = tile[(cg * 4 + 3) * 65 + krow];
        *(float4*)&wt[(size_t)(k0 + krow) * 1024 + c0 + cg * 4] = v;
    }
}

// ---------------------------------------------------------------------------
// k1: zsq[p] / wsq[c] with numpy pairwise order (128+128, 8 accumulators)
// ---------------------------------------------------------------------------
__global__ void k1_sums(const float* __restrict__ z, const float* __restrict__ wemb,
                        float* __restrict__ zsq, float* __restrict__ wsq) {
    const int b = blockIdx.x;
    const int tid = threadIdx.x;
    if (b < 128) {
        const int p = b * 256 + tid;
        const int n = p >> 10, hw = p & 1023;
        const float* base = z + (((size_t)(n * 256)) << 10) + hw;
        float half[2];
        #pragma unroll
        for (int h = 0; h < 2; ++h) {
            const float* x = base + (((size_t)(h * 128)) << 10);
            float r[8];
            #pragma unroll
            for (int j = 0; j < 8; ++j) r[j] = sq_sep(x[((size_t)j) << 10]);
            for (int i = 8; i < 128; i += 8) {
                #pragma unroll
                for (int j = 0; j < 8; ++j) r[j] += sq_sep(x[((size_t)(i + j)) << 10]);
            }
            half[h] = ((r[0] + r[1]) + (r[2] + r[3])) + ((r[4] + r[5]) + (r[6] + r[7]));
        }
        zsq[p] = half[0] + half[1];
    } else {
        const int c = (b - 128) * 256 + tid;
        const float* base = wemb + (size_t)c * 256;
        float half[2];
        #pragma unroll
        for (int h = 0; h < 2; ++h) {
            const float* x = base + h * 128;
            float r[8];
            #pragma unroll
            for (int j = 0; j < 8; ++j) r[j] = sq_sep(x[j]);
            for (int i = 8; i < 128; i += 8) {
                #pragma unroll
                for (int j = 0; j < 8; ++j) r[j] += sq_sep(x[i + j]);
            }
            half[h] = ((r[0] + r[1]) + (r[2] + r[3])) + ((r[4] + r[5]) + (r[6] + r[7]));
        }
        wsq[c] = half[0] + half[1];
    }
}

// ---------------------------------------------------------------------------
// k2: fused GEMM + argmin. Block = 128 positions x 256 codes (one quarter).
// Grid 1024: pg = (bid&7)|((bid>>5)<<3), q = (bid>>3)&3  (all 4 quarters of a
// pg land on one XCD, close in time -> z tile L2-shared).
// 256 threads = 16 tr x 16 tc; per thread 8 pos x 16 codes (acc[8][16]).
// K streamed in 16 chunks of 16, double-buffered LDS, loads issued one tile
// ahead (T3 2-phase), single barrier per tile.
// fma chain strictly k-ascending => bitwise-identical distances to R1.
// ---------------------------------------------------------------------------
__launch_bounds__(256, 2)
__global__ void k2_argmin(const float* __restrict__ z, const float* __restrict__ wt,
                          const float* __restrict__ zsq, const float* __restrict__ wsq,
                          float* __restrict__ pd, float* __restrict__ pi) {
    __shared__ float As[2][16 * 128];   // [k][m] 8 KB x2
    __shared__ float Bs[2][16 * 256];   // [k][c] 16 KB x2
    __shared__ float wsqs[256];

    const int tid = threadIdx.x;
    const int bid = blockIdx.x;
    const int pg = (bid & 7) | ((bid >> 5) << 3);
    const int q  = (bid >> 3) & 3;
    const int tc = tid & 15, tr = tid >> 4;
    const int w = tid >> 6, l = tid & 63;
    const int p0 = pg * 128;
    const int nb = (p0 >> 10) * 256;    // n*256
    const int hw0 = p0 & 1023;
    const int cq256 = q * 256;

    wsqs[tid] = wsq[cq256 + tid];

    float zr[8];
    #pragma unroll
    for (int m = 0; m < 8; ++m) zr[m] = zsq[p0 + tr * 8 + m];

    float acc[8][16];
    #pragma unroll
    for (int m = 0; m < 8; ++m)
        #pragma unroll
        for (int j = 0; j < 16; ++j) acc[m][j] = 0.0f;

#define STAGE(buf, kc_) do {                                                   \
    const int kb_ = (kc_) * 16;                                                \
    _Pragma("unroll")                                                          \
    for (int i_ = 0; i_ < 2; ++i_) {                                           \
        const int r_ = (w * 2 + i_) * 2 + (l >> 5);                            \
        GLOAD16(z + ((size_t)(nb + kb_ + r_) << 10) + hw0 + (l & 31) * 4,      \
                &As[buf][(w * 2 + i_) * 256]);                                 \
    }                                                                          \
    _Pragma("unroll")                                                          \
    for (int j_ = 0; j_ < 4; ++j_) {                                           \
        const int r_ = w * 4 + j_;                                             \
        GLOAD16(wt + ((size_t)(kb_ + r_) << 10) + cq256 + l * 4,               \
                &Bs[buf][r_ * 256]);                                           \
    }                                                                          \
} while (0)

    STAGE(0, 0);
    __syncthreads();                     // prologue drain (once)

    for (int kc = 0; kc < 16; ++kc) {
        const int cur = kc & 1;
        if (kc < 15) STAGE(cur ^ 1, kc + 1);   // next tile in flight over compute
        #pragma unroll
        for (int kk = 0; kk < 16; ++kk) {
            const float4 a0 = *(const float4*)&As[cur][kk * 128 + tr * 8];
            const float4 a1 = *(const float4*)&As[cur][kk * 128 + tr * 8 + 4];
            const float am[8] = {a0.x, a0.y, a0.z, a0.w, a1.x, a1.y, a1.z, a1.w};
            float bb[16];
            #pragma unroll
            for (int j = 0; j < 4; ++j) {
                const float4 b = *(const float4*)&Bs[cur][kk * 256 + j * 64 + tc * 4];
                bb[j * 4 + 0] = b.x; bb[j * 4 + 1] = b.y;
                bb[j * 4 + 2] = b.z; bb[j * 4 + 3] = b.w;
            }
            #pragma unroll
            for (int m = 0; m < 8; ++m)
                #pragma unroll
                for (int j = 0; j < 16; ++j)
                    acc[m][j] = __builtin_fmaf(am[m], bb[j], acc[m][j]);
        }
        __syncthreads();   // implicit vmcnt(0): next tile landed; cur free to reuse
    }
#undef STAGE

    // argmin epilogue (ascending code order within thread; strict < = first wins)
    #pragma unroll
    for (int m = 0; m < 8; ++m) {
        float bd = FLT_MAX;
        int bi = 0;
        #pragma unroll
        for (int j = 0; j < 4; ++j)
            #pragma unroll
            for (int e = 0; e < 4; ++e) {
                const int cl = j * 64 + tc * 4 + e;
                const float d = __builtin_fmaf(-2.0f, acc[m][j * 4 + e], zr[m]) + wsqs[cl];
                if (d < bd) { bd = d; bi = cq256 + cl; }
            }
        #pragma unroll
        for (int off = 1; off < 16; off <<= 1) {
            const float od = __shfl_xor(bd, off);
            const int   oi = __shfl_xor(bi, off);
            if (od < bd || (od == bd && oi < bi)) { bd = od; bi = oi; }
        }
        if (tc == 0) {
            pd[q * P_TOTAL + p0 + tr * 8 + m] = bd;
            pi[q * P_TOTAL + p0 + tr * 8 + m] = (float)bi;
        }
    }
}

// ---------------------------------------------------------------------------
// k2b: combine the four code-quarters (ascending q, strict < -> lowest index)
// ---------------------------------------------------------------------------
__global__ void k2b_combine(const float* __restrict__ pd, const float* __restrict__ pi,
                            float* __restrict__ idx_out) {
    const int p = blockIdx.x * 256 + threadIdx.x;
    float bd = pd[p];
    float bi = pi[p];
    #pragma unroll
    for (int qq = 1; qq < 4; ++qq) {
        const float d = pd[qq * P_TOTAL + p];
        if (d < bd) { bd = d; bi = pi[qq * P_TOTAL + p]; }
    }
    idx_out[p] = bi;
}

// ---------------------------------------------------------------------------
// k3: gather + straight-through, NCHW float4 writes
// ---------------------------------------------------------------------------
__global__ void k3_gather(const float* __restrict__ z, const float* __restrict__ wemb,
                          const float* __restrict__ idxf,
                          float* __restrict__ out0, float* __restrict__ out1) {
    const int t = blockIdx.x * 256 + threadIdx.x;
    const int hw4 = t & 255, c = (t >> 8) & 255, n = t >> 16;
    const size_t zo = (((size_t)(n * 256 + c)) << 10) + hw4 * 4;
    const float4 zv = *(const float4*)&z[zo];
    const float4 iv = *(const float4*)&idxf[n * 1024 + hw4 * 4];
    float4 qv, st;
    {
        const int i0 = (int)iv.x; qv.x = wemb[(size_t)i0 * 256 + c]; st.x = (qv.x - zv.x) + zv.x;
        const int i1 = (int)iv.y; qv.y = wemb[(size_t)i1 * 256 + c]; st.y = (qv.y - zv.y) + zv.y;
        const int i2 = (int)iv.z; qv.z = wemb[(size_t)i2 * 256 + c]; st.z = (qv.z - zv.z) + zv.z;
        const int i3 = (int)iv.w; qv.w = wemb[(size_t)i3 * 256 + c]; st.w = (qv.w - zv.w) + zv.w;
    }
    *(float4*)&out0[zo] = qv;
    *(float4*)&out1[zo] = st;
}

extern "C" void kernel_launch(void* const* d_in, const int* in_sizes, int n_in,
                              void* d_out, int out_size, void* d_ws, size_t ws_size,
                              hipStream_t stream) {
    const float* z = (const float*)d_in[0];
    const float* wemb = (const float*)d_in[1];
    float* out = (float*)d_out;
    float* out0 = out;
    float* out1 = out + Q_ELEMS;
    float* oidx = out + 2 * Q_ELEMS;
    float* ws = (float*)d_ws;
    float* zsq = ws + WS_ZSQ;
    float* wsq = ws + WS_WSQ;
    float* pd  = ws + WS_PD;
    float* pi  = ws + WS_PI;
    float* wt  = ws + WS_WT;

    k0_transpose<<<64, 256, 0, stream>>>(wemb, wt);
    k1_sums<<<132, 256, 0, stream>>>(z, wemb, zsq, wsq);
    k2_argmin<<<1024, 256, 0, stream>>>(z, wt, zsq, wsq, pd, pi);
    k2b_combine<<<128, 256, 0, stream>>>(pd, pi, oidx);
    k3_gather<<<Q_ELEMS / 4 / 256, 256, 0, stream>>>(z, wemb, oidx, out0, out1);
}